// Round 5
// baseline (408.258 us; speedup 1.0000x reference)
//
#include <hip/hip_runtime.h>
#include <cstdint>
#include <cmath>

#define HID 768
#define INNER 1536
#define NST 16
#define SEQ 2048
#define BATCH 2
#define MTOK 4096      // BATCH*SEQ
#define CHUNK 32
#define NCHUNK 64      // SEQ/CHUNK
#define LOG2E 1.44269504088896f

typedef unsigned short u16;
typedef __bf16 bf16x8 __attribute__((ext_vector_type(8)));
typedef float f32x4 __attribute__((ext_vector_type(4)));
typedef u16 u16x8 __attribute__((ext_vector_type(8)));

__device__ __forceinline__ u16 f2b(float f) {
  union { float f; unsigned u; } a; a.f = f;
  unsigned r = a.u + 0x7FFFu + ((a.u >> 16) & 1u);
  return (u16)(r >> 16);
}
__device__ __forceinline__ float b2f(u16 h) {
  union { unsigned u; float f; } a; a.u = ((unsigned)h) << 16; return a.f;
}

// packed fragment layout: element (m,k) of an [M][K] bf16 matrix lives at
//   chunk = ((m>>4)*KS + (k>>5))*64 + ((k>>3)&3)*16 + (m&15),  elem = chunk*8 + (k&7)
// where KS = K/32. A wave reading tile t, kstep ks loads 64 lanes x 16B contiguous.
__device__ __forceinline__ long pidx(long m, int k, int KS) {
  return (((m >> 4) * (long)KS + (k >> 5)) * 64 + ((k >> 3) & 3) * 16 + (m & 15)) * 8 + (k & 7);
}

// ---------------- LayerNorm + cast to bf16 (packed, KS=24) ----------------
__global__ __launch_bounds__(256)
void ln_kernel(const float* __restrict__ x, const float* __restrict__ w,
               const float* __restrict__ b, u16* __restrict__ xnp) {
  const long row = blockIdx.x;
  const float* xr = x + row * HID;
  const int t = threadIdx.x;
  float v0 = xr[t], v1 = xr[t + 256], v2 = xr[t + 512];
  float s1 = v0 + v1 + v2;
  float s2 = v0 * v0 + v1 * v1 + v2 * v2;
#pragma unroll
  for (int o = 32; o > 0; o >>= 1) { s1 += __shfl_down(s1, o); s2 += __shfl_down(s2, o); }
  __shared__ float r1[4], r2[4];
  if ((t & 63) == 0) { r1[t >> 6] = s1; r2[t >> 6] = s2; }
  __syncthreads();
  s1 = r1[0] + r1[1] + r1[2] + r1[3];
  s2 = r2[0] + r2[1] + r2[2] + r2[3];
  const float mu = s1 * (1.f / HID);
  float var = s2 * (1.f / HID) - mu * mu;
  const float rs = rsqrtf(var + 1e-5f);
  xnp[pidx(row, t,       24)] = f2b((v0 - mu) * rs * w[t]       + b[t]);
  xnp[pidx(row, t + 256, 24)] = f2b((v1 - mu) * rs * w[t + 256] + b[t + 256]);
  xnp[pidx(row, t + 512, 24)] = f2b((v2 - mu) * rs * w[t + 512] + b[t + 512]);
}

// ---------------- fp32 W[K][N] -> packed bf16 fragments (B-operand) ----------------
// grid (Npad/64, K/32), block 256. Zero-pads cols >= N.
__global__ __launch_bounds__(256)
void pack_w(const float* __restrict__ W, u16* __restrict__ Bp, int K, int N) {
  __shared__ float tb[32][65];
  const int t = threadIdx.x;
  const int n0 = blockIdx.x * 64;
  const int ks = blockIdx.y;
  const int k0 = ks * 32;
  const int KS = K >> 5;
  {
    const int col = t & 63, row0 = t >> 6;
    const int nn = n0 + col;
#pragma unroll
    for (int rr = 0; rr < 8; ++rr) {
      const int kk = k0 + row0 + rr * 4;
      tb[row0 + rr * 4][col] = (nn < N) ? W[(long)kk * N + nn] : 0.f;
    }
  }
  __syncthreads();
  const int ntl = t >> 6, l4 = (t >> 4) & 3, l16 = t & 15;
  const int nl = ntl * 16 + l16;
  u16x8 outv;
#pragma unroll
  for (int wdx = 0; wdx < 8; ++wdx) outv[wdx] = f2b(tb[l4 * 8 + wdx][nl]);
  const long tile = (n0 >> 4) + ntl;
  *(u16x8*)&Bp[(tile * KS + ks) * 512 + (l4 * 16 + l16) * 8] = outv;
}

// ---------------- register-direct packed GEMM, no LDS, no barriers ------------
// wave tile = FI*16 x FJ*16; block = 2x2 waves; grid = (WM/2)*NBLK blocks,
// XCD-striped. A, B both in packed fragment layout.
// EPI 0: cc<1536 -> xpu fp32; else sg = bf16(silu(v))         (gemm0)
// EPI 1: cc<16 -> Bm f32; cc<32 -> Cm f32; cc<Nstore -> dlt bf16(softplus)
// EPI 2: zbp[pidx(row,cc,48)] = bf16(v * sg[row,cc])           (gemm2)
// EPI 3: O0[row*768+cc] = v + Ef[row*768+cc]                   (gemm3)
template <int FI, int FJ, int NBLK, int EPI>
__global__ __launch_bounds__(256)
void gemm_pk(const u16* __restrict__ Ap, const u16* __restrict__ Bp,
             float* __restrict__ O0, float* __restrict__ O1, u16* __restrict__ O2,
             const float* __restrict__ Ef, const u16* __restrict__ Eb,
             int K, int Nstore) {
  constexpr int WM = 256 / FI;        // wave rows total (M=4096)
  constexpr int PERX = WM / 16;       // wave-pair rows per XCD
  const int KS = K >> 5;
  const int u = blockIdx.x;
  const int wave = threadIdx.x >> 6;
  const int lane = threadIdx.x & 63;
  const int xcd = u & 7;
  const int s = u >> 3;
  const int wmrow = (xcd * PERX + s / NBLK) * 2 + (wave >> 1);
  const int wn = (s % NBLK) * 2 + (wave & 1);

  const u16* a0 = Ap + ((long)(wmrow * FI) * KS * 64 + lane) * 8;
  const u16* b0 = Bp + ((long)(wn * FJ) * KS * 64 + lane) * 8;

  f32x4 acc[FI][FJ] = {};
  bf16x8 afA[FI], bfA[FJ], afB[FI], bfB[FJ];

#pragma unroll
  for (int i = 0; i < FI; ++i) afA[i] = *(const bf16x8*)(a0 + (long)i * KS * 512);
#pragma unroll
  for (int j = 0; j < FJ; ++j) bfA[j] = *(const bf16x8*)(b0 + (long)j * KS * 512);

  for (int ks = 0; ks < KS; ks += 2) {
    // prefetch ks+1 while computing ks
#pragma unroll
    for (int i = 0; i < FI; ++i) afB[i] = *(const bf16x8*)(a0 + ((long)i * KS + ks + 1) * 512);
#pragma unroll
    for (int j = 0; j < FJ; ++j) bfB[j] = *(const bf16x8*)(b0 + ((long)j * KS + ks + 1) * 512);
#pragma unroll
    for (int i = 0; i < FI; ++i)
#pragma unroll
      for (int j = 0; j < FJ; ++j)
        acc[i][j] = __builtin_amdgcn_mfma_f32_16x16x32_bf16(afA[i], bfA[j], acc[i][j], 0, 0, 0);
    if (ks + 2 < KS) {
#pragma unroll
      for (int i = 0; i < FI; ++i) afA[i] = *(const bf16x8*)(a0 + ((long)i * KS + ks + 2) * 512);
#pragma unroll
      for (int j = 0; j < FJ; ++j) bfA[j] = *(const bf16x8*)(b0 + ((long)j * KS + ks + 2) * 512);
    }
#pragma unroll
    for (int i = 0; i < FI; ++i)
#pragma unroll
      for (int j = 0; j < FJ; ++j)
        acc[i][j] = __builtin_amdgcn_mfma_f32_16x16x32_bf16(afB[i], bfB[j], acc[i][j], 0, 0, 0);
  }

  const int l16 = lane & 15, l4 = lane >> 4;
#pragma unroll
  for (int i = 0; i < FI; ++i) {
    const long rr = (long)(wmrow * FI + i) * 16 + l4 * 4;
#pragma unroll
    for (int j = 0; j < FJ; ++j) {
      const int cc = (wn * FJ + j) * 16 + l16;
#pragma unroll
      for (int r = 0; r < 4; ++r) {
        const long row = rr + r;
        const float v = acc[i][j][r];
        if (EPI == 0) {
          if (cc < 1536) O0[row * 1536 + cc] = v;
          else {
            float sv = v / (1.f + __expf(-v));
            O2[row * 1536 + (cc - 1536)] = f2b(sv);
          }
        } else if (EPI == 1) {
          if (cc < 16) O0[row * 16 + cc] = v;
          else if (cc < 32) O1[row * 16 + (cc - 16)] = v;
          else if (cc < Nstore) {
            float sp = (v > 20.f) ? v : log1pf(__expf(v));
            O2[row * 1536 + (cc - 32)] = f2b(sp);
          }
        } else if (EPI == 2) {
          float g = b2f(Eb[row * 1536 + cc]);
          O2[pidx(row, cc, 48)] = f2b(v * g);
        } else {
          O0[row * 768 + cc] = v + Ef[row * 768 + cc];
        }
      }
    }
  }
}

// ---------------- depthwise causal conv(K=4) + SiLU -> flat + packed bf16 -------
__global__ __launch_bounds__(256)
void conv_silu(const float* __restrict__ xpu, const float* __restrict__ cw,
               u16* __restrict__ ub, u16* __restrict__ ubp) {
  const int c = blockIdx.x * 256 + threadIdx.x;
  const long m = blockIdx.y;
  const int t = (int)(m & (SEQ - 1));
  const float w0 = cw[c * 4 + 0], w1 = cw[c * 4 + 1], w2 = cw[c * 4 + 2], w3 = cw[c * 4 + 3];
  float acc = w3 * xpu[m * 1536 + c];
  if (t >= 1) acc += w2 * xpu[(m - 1) * 1536 + c];
  if (t >= 2) acc += w1 * xpu[(m - 2) * 1536 + c];
  if (t >= 3) acc += w0 * xpu[(m - 3) * 1536 + c];
  const float s = acc / (1.f + __expf(-acc));
  const u16 sb = f2b(s);
  ub[m * 1536 + c] = sb;
  ubp[pidx(m, c, 48)] = sb;
}

// ---------------- scan phase A: per-chunk (P, Q) from h=0, 4 states/thread ------
__global__ __launch_bounds__(256)
void scan_phaseA(const u16* __restrict__ dlt, const u16* __restrict__ ub,
                 const float* __restrict__ Bm, const float* __restrict__ A_log,
                 float* __restrict__ P, float* __restrict__ Q) {
  const int tid = threadIdx.x;
  const int cl = tid >> 2;
  const int sg = tid & 3;
  const int c = blockIdx.x * 64 + cl;
  const int b = blockIdx.y;
  const int ch = blockIdx.z;
  float a2[4];
#pragma unroll
  for (int j = 0; j < 4; ++j) a2[j] = -__expf(A_log[sg * 4 + j]) * LOG2E;
  float h[4] = {0.f, 0.f, 0.f, 0.f};
  float sumd = 0.f;
  const long base = (long)b * SEQ + (long)ch * CHUNK;
  for (int t = 0; t < CHUNK; ++t) {
    const long m = base + t;
    const float d = b2f(dlt[m * 1536 + c]);
    const float du = d * b2f(ub[m * 1536 + c]);
    sumd += d;
    const f32x4 Bv = *(const f32x4*)&Bm[m * 16 + sg * 4];
#pragma unroll
    for (int j = 0; j < 4; ++j) {
      const float e = exp2f(a2[j] * d);
      h[j] = e * h[j] + du * Bv[j];
    }
  }
  const long sb = (((long)b * NCHUNK + ch) * NST + sg * 4) * 1536 + c;
#pragma unroll
  for (int j = 0; j < 4; ++j) {
    Q[sb + (long)j * 1536] = h[j];
    P[sb + (long)j * 1536] = exp2f(a2[j] * sumd);
  }
}

// ---------------- scan phase B: serial combine over chunks (hs aliases P) -------
__global__ __launch_bounds__(256)
void scan_phaseB(float* __restrict__ P, const float* __restrict__ Q) {
  const long g = (long)blockIdx.x * 256 + threadIdx.x;   // BATCH*NST*INNER
  const int c = (int)(g % 1536);
  const int n = (int)((g / 1536) % NST);
  const int b = (int)(g / (1536 * NST));
  float h = 0.f;
  for (int ch = 0; ch < NCHUNK; ++ch) {
    const long idx = (((long)b * NCHUNK + ch) * NST + n) * 1536 + c;
    const float p = P[idx];
    const float q = Q[idx];
    P[idx] = h;              // hs written in place of P (read-before-write)
    h = p * h + q;
  }
}

// ---------------- scan phase C: replay with true h_start, emit ys packed --------
__global__ __launch_bounds__(256)
void scan_phaseC(const u16* __restrict__ dlt, const u16* __restrict__ ub,
                 const float* __restrict__ Bm, const float* __restrict__ Cm,
                 const float* __restrict__ A_log, const float* __restrict__ Dv,
                 const float* __restrict__ hs, u16* __restrict__ ysp) {
  const int tid = threadIdx.x;
  const int cl = tid >> 2;
  const int sg = tid & 3;
  const int c = blockIdx.x * 64 + cl;
  const int b = blockIdx.y;
  const int ch = blockIdx.z;
  float a2[4];
#pragma unroll
  for (int j = 0; j < 4; ++j) a2[j] = -__expf(A_log[sg * 4 + j]) * LOG2E;
  float h[4];
  const long sb = (((long)b * NCHUNK + ch) * NST + sg * 4) * 1536 + c;
#pragma unroll
  for (int j = 0; j < 4; ++j) h[j] = hs[sb + (long)j * 1536];
  const float Dc = Dv[c];
  const long base = (long)b * SEQ + (long)ch * CHUNK;
  for (int t = 0; t < CHUNK; ++t) {
    const long m = base + t;
    const float d = b2f(dlt[m * 1536 + c]);
    const float uu = b2f(ub[m * 1536 + c]);
    const float du = d * uu;
    const f32x4 Bv = *(const f32x4*)&Bm[m * 16 + sg * 4];
    const f32x4 Cv = *(const f32x4*)&Cm[m * 16 + sg * 4];
    float y = (sg == 0) ? Dc * uu : 0.f;
#pragma unroll
    for (int j = 0; j < 4; ++j) {
      const float e = exp2f(a2[j] * d);
      h[j] = e * h[j] + du * Bv[j];
      y += h[j] * Cv[j];
    }
    y += __shfl_xor(y, 1);
    y += __shfl_xor(y, 2);
    if (sg == 0) ysp[pidx(m, c, 48)] = f2b(y);
  }
}

extern "C" void kernel_launch(void* const* d_in, const int* in_sizes, int n_in,
                              void* d_out, int out_size, void* d_ws, size_t ws_size,
                              hipStream_t stream) {
  const float* x     = (const float*)d_in[0];
  const float* nw    = (const float*)d_in[1];
  const float* nb    = (const float*)d_in[2];
  const float* W_in  = (const float*)d_in[3];
  const float* cw    = (const float*)d_in[4];
  const float* W_xp  = (const float*)d_in[5];
  const float* A_log = (const float*)d_in[6];
  const float* Dv    = (const float*)d_in[7];
  const float* W_so  = (const float*)d_in[8];
  const float* W_out = (const float*)d_in[9];
  float* out = (float*)d_out;

  char* w = (char*)d_ws;
  auto alloc = [&](size_t bytes) {
    char* p = w;
    w += (bytes + 255) & ~(size_t)255;
    return p;
  };
  u16*   xnp   = (u16*)  alloc((size_t)MTOK * HID * 2);    // packed, KS=24
  u16*   WpIn  = (u16*)  alloc((size_t)3072 * 768 * 2);    // packed
  float* xpu   = (float*)alloc((size_t)MTOK * 1536 * 4);   // u half, fp32 flat
  u16*   sg    = (u16*)  alloc((size_t)MTOK * 1536 * 2);   // silu(gate), bf16 flat
  u16*   ub    = (u16*)  alloc((size_t)MTOK * 1536 * 2);   // silu(conv(u)), flat
  u16*   ubp   = (u16*)  alloc((size_t)MTOK * 1536 * 2);   // same, packed KS=48
  u16*   WpXp  = (u16*)  alloc((size_t)1664 * 1536 * 2);   // packed
  float* Bmv   = (float*)alloc((size_t)MTOK * 16 * 4);
  float* Cmv   = (float*)alloc((size_t)MTOK * 16 * 4);
  u16*   dlt   = (u16*)  alloc((size_t)MTOK * 1536 * 2);   // softplus(delta), flat
  float* P     = (float*)alloc((size_t)BATCH * NCHUNK * NST * 1536 * 4);  // becomes hs
  float* Q     = (float*)alloc((size_t)BATCH * NCHUNK * NST * 1536 * 4);
  u16*   ysp   = (u16*)  alloc((size_t)MTOK * 1536 * 2);   // packed KS=48
  u16*   WpSo  = (u16*)  alloc((size_t)1536 * 1536 * 2);   // packed
  u16*   zbp   = (u16*)  alloc((size_t)MTOK * 1536 * 2);   // packed KS=48
  u16*   WpOut = (u16*)  alloc((size_t)768 * 1536 * 2);    // packed

  ln_kernel<<<MTOK, 256, 0, stream>>>(x, nw, nb, xnp);
  pack_w<<<dim3(48, 24), 256, 0, stream>>>(W_in,  WpIn,  768,  3072);
  pack_w<<<dim3(26, 48), 256, 0, stream>>>(W_xp,  WpXp,  1536, 1568);
  pack_w<<<dim3(24, 48), 256, 0, stream>>>(W_so,  WpSo,  1536, 1536);
  pack_w<<<dim3(12, 48), 256, 0, stream>>>(W_out, WpOut, 1536, 768);

  // gemm0: 4096x3072, K=768.  FI=4 FJ=4: WM=64, WN=48, NBLK=24 -> 768 blocks
  gemm_pk<4, 4, 24, 0><<<768, 256, 0, stream>>>(xnp, WpIn, xpu, nullptr, sg, nullptr, nullptr, 768, 3072);
  conv_silu<<<dim3(6, MTOK), 256, 0, stream>>>(xpu, cw, ub, ubp);
  // gemm1: 4096x1664, K=1536. FI=4 FJ=2: WM=64, WN=52, NBLK=26 -> 832 blocks
  gemm_pk<4, 2, 26, 1><<<832, 256, 0, stream>>>(ubp, WpXp, Bmv, Cmv, dlt, nullptr, nullptr, 1536, 1568);
  scan_phaseA<<<dim3(24, 2, NCHUNK), 256, 0, stream>>>(dlt, ub, Bmv, A_log, P, Q);
  scan_phaseB<<<192, 256, 0, stream>>>(P, Q);
  scan_phaseC<<<dim3(24, 2, NCHUNK), 256, 0, stream>>>(dlt, ub, Bmv, Cmv, A_log, Dv, P, ysp);
  // gemm2: 4096x1536, K=1536. FI=4 FJ=2: WN=48, NBLK=24 -> 768 blocks
  gemm_pk<4, 2, 24, 2><<<768, 256, 0, stream>>>(ysp, WpSo, nullptr, nullptr, zbp, nullptr, sg, 1536, 1536);
  // gemm3: 4096x768,  K=1536. FI=2 FJ=2: WM=128, WN=24, NBLK=12 -> 768 blocks
  gemm_pk<2, 2, 12, 3><<<768, 256, 0, stream>>>(zbp, WpOut, out, nullptr, nullptr, x, nullptr, 1536, 768);
}

// Round 6
// 401.317 us; speedup vs baseline: 1.0173x; 1.0173x over previous
//
#include <hip/hip_runtime.h>
#include <cstdint>
#include <cmath>

#define HID 768
#define INNER 1536
#define NST 16
#define SEQ 2048
#define BATCH 2
#define MTOK 4096      // BATCH*SEQ
#define CHUNK 32
#define NCHUNK 64      // SEQ/CHUNK
#define LOG2E 1.44269504088896f

typedef unsigned short u16;
typedef __bf16 bf16x8 __attribute__((ext_vector_type(8)));
typedef float f32x4 __attribute__((ext_vector_type(4)));
typedef u16 u16x8 __attribute__((ext_vector_type(8)));

__device__ __forceinline__ u16 f2b(float f) {
  union { float f; unsigned u; } a; a.f = f;
  unsigned r = a.u + 0x7FFFu + ((a.u >> 16) & 1u);
  return (u16)(r >> 16);
}
__device__ __forceinline__ float b2f(u16 h) {
  union { unsigned u; float f; } a; a.u = ((unsigned)h) << 16; return a.f;
}

// packed fragment layout: element (m,k) of an [M][K] bf16 matrix lives at
//   chunk = ((m>>4)*KS + (k>>5))*64 + ((k>>3)&3)*16 + (m&15),  elem = chunk*8 + (k&7)
// where KS = K/32. A wave reading tile t, kstep ks loads 64 lanes x 16B contiguous.
__device__ __forceinline__ long pidx(long m, int k, int KS) {
  return (((m >> 4) * (long)KS + (k >> 5)) * 64 + ((k >> 3) & 3) * 16 + (m & 15)) * 8 + (k & 7);
}

// ---------------- LayerNorm + cast to bf16 (packed, KS=24) ----------------
__global__ __launch_bounds__(256)
void ln_kernel(const float* __restrict__ x, const float* __restrict__ w,
               const float* __restrict__ b, u16* __restrict__ xnp) {
  const long row = blockIdx.x;
  const float* xr = x + row * HID;
  const int t = threadIdx.x;
  float v0 = xr[t], v1 = xr[t + 256], v2 = xr[t + 512];
  float s1 = v0 + v1 + v2;
  float s2 = v0 * v0 + v1 * v1 + v2 * v2;
#pragma unroll
  for (int o = 32; o > 0; o >>= 1) { s1 += __shfl_down(s1, o); s2 += __shfl_down(s2, o); }
  __shared__ float r1[4], r2[4];
  if ((t & 63) == 0) { r1[t >> 6] = s1; r2[t >> 6] = s2; }
  __syncthreads();
  s1 = r1[0] + r1[1] + r1[2] + r1[3];
  s2 = r2[0] + r2[1] + r2[2] + r2[3];
  const float mu = s1 * (1.f / HID);
  float var = s2 * (1.f / HID) - mu * mu;
  const float rs = rsqrtf(var + 1e-5f);
  xnp[pidx(row, t,       24)] = f2b((v0 - mu) * rs * w[t]       + b[t]);
  xnp[pidx(row, t + 256, 24)] = f2b((v1 - mu) * rs * w[t + 256] + b[t + 256]);
  xnp[pidx(row, t + 512, 24)] = f2b((v2 - mu) * rs * w[t + 512] + b[t + 512]);
}

// ---------------- fp32 W[K][N] -> packed bf16 fragments (B-operand) ----------------
__global__ __launch_bounds__(256)
void pack_w(const float* __restrict__ W, u16* __restrict__ Bp, int K, int N) {
  __shared__ float tb[32][65];
  const int t = threadIdx.x;
  const int n0 = blockIdx.x * 64;
  const int ks = blockIdx.y;
  const int k0 = ks * 32;
  const int KS = K >> 5;
  {
    const int col = t & 63, row0 = t >> 6;
    const int nn = n0 + col;
#pragma unroll
    for (int rr = 0; rr < 8; ++rr) {
      const int kk = k0 + row0 + rr * 4;
      tb[row0 + rr * 4][col] = (nn < N) ? W[(long)kk * N + nn] : 0.f;
    }
  }
  __syncthreads();
  const int ntl = t >> 6, l4 = (t >> 4) & 3, l16 = t & 15;
  const int nl = ntl * 16 + l16;
  u16x8 outv;
#pragma unroll
  for (int wdx = 0; wdx < 8; ++wdx) outv[wdx] = f2b(tb[l4 * 8 + wdx][nl]);
  const long tile = (n0 >> 4) + ntl;
  *(u16x8*)&Bp[(tile * KS + ks) * 512 + (l4 * 16 + l16) * 8] = outv;
}

// ---------------- register-direct packed GEMM, 3-deep SW pipeline ------------
// No LDS, no barriers. While computing stage s, loads for s+1 and s+2 are in
// flight (2 full stage-computes of latency coverage). Pointer-bump addressing:
// stage offsets 0/1024/2048 bytes as load immediates, +3072 B per iteration.
template <int FI, int FJ, int NBLK, int EPI>
__global__ __launch_bounds__(256)
void gemm_pk(const u16* __restrict__ Ap, const u16* __restrict__ Bp,
             float* __restrict__ O0, float* __restrict__ O1, u16* __restrict__ O2,
             const float* __restrict__ Ef, const u16* __restrict__ Eb,
             int K, int Nstore) {
  constexpr int WM = 256 / FI;        // wave rows total (M=4096)
  constexpr int PERX = WM / 16;       // wave-pair rows per XCD
  const int KS = K >> 5;              // k-steps (multiple of 3)
  const int u = blockIdx.x;
  const int wave = threadIdx.x >> 6;
  const int lane = threadIdx.x & 63;
  const int xcd = u & 7;
  const int s = u >> 3;
  const int wmrow = (xcd * PERX + s / NBLK) * 2 + (wave >> 1);
  const int wn = (s % NBLK) * 2 + (wave & 1);

  const u16* pa[FI];
  const u16* pb[FJ];
#pragma unroll
  for (int i = 0; i < FI; ++i)
    pa[i] = Ap + ((long)(wmrow * FI + i) * KS * 64 + lane) * 8;
#pragma unroll
  for (int j = 0; j < FJ; ++j)
    pb[j] = Bp + ((long)(wn * FJ + j) * KS * 64 + lane) * 8;

  f32x4 acc[FI][FJ] = {};
  bf16x8 fa0[FI], fa1[FI], fa2[FI], fb0[FJ], fb1[FJ], fb2[FJ];

  auto rld = [&](bf16x8 (&A)[FI], bf16x8 (&B)[FJ], int off) {
#pragma unroll
    for (int i = 0; i < FI; ++i) A[i] = *(const bf16x8*)(pa[i] + off);
#pragma unroll
    for (int j = 0; j < FJ; ++j) B[j] = *(const bf16x8*)(pb[j] + off);
  };
  auto comp = [&](bf16x8 (&A)[FI], bf16x8 (&B)[FJ]) {
#pragma unroll
    for (int i = 0; i < FI; ++i)
#pragma unroll
      for (int j = 0; j < FJ; ++j)
        acc[i][j] = __builtin_amdgcn_mfma_f32_16x16x32_bf16(A[i], B[j], acc[i][j], 0, 0, 0);
  };
  auto bump = [&]() {
#pragma unroll
    for (int i = 0; i < FI; ++i) pa[i] += 1536;
#pragma unroll
    for (int j = 0; j < FJ; ++j) pb[j] += 1536;
  };

  // prologue: stages for ks = 0,1,2
  rld(fa0, fb0, 0);
  rld(fa1, fb1, 512);
  rld(fa2, fb2, 1024);
  bump();

  const int iters = KS / 3 - 1;
  for (int it = 0; it < iters; ++it) {
    comp(fa0, fb0); rld(fa0, fb0, 0);
    comp(fa1, fb1); rld(fa1, fb1, 512);
    comp(fa2, fb2); rld(fa2, fb2, 1024);
    bump();
  }
  comp(fa0, fb0);
  comp(fa1, fb1);
  comp(fa2, fb2);

  const int l16 = lane & 15, l4 = lane >> 4;
#pragma unroll
  for (int i = 0; i < FI; ++i) {
    const long rr = (long)(wmrow * FI + i) * 16 + l4 * 4;
#pragma unroll
    for (int j = 0; j < FJ; ++j) {
      const int cc = (wn * FJ + j) * 16 + l16;
#pragma unroll
      for (int r = 0; r < 4; ++r) {
        const long row = rr + r;
        const float v = acc[i][j][r];
        if (EPI == 0) {
          if (cc < 1536) O0[row * 1536 + cc] = v;
          else {
            float sv = v / (1.f + __expf(-v));
            O2[row * 1536 + (cc - 1536)] = f2b(sv);
          }
        } else if (EPI == 1) {
          if (cc < 16) O0[row * 16 + cc] = v;
          else if (cc < 32) O1[row * 16 + (cc - 16)] = v;
          else if (cc < Nstore) {
            float sp = (v > 20.f) ? v : log1pf(__expf(v));
            O2[row * 1536 + (cc - 32)] = f2b(sp);
          }
        } else if (EPI == 2) {
          float g = b2f(Eb[row * 1536 + cc]);
          O2[pidx(row, cc, 48)] = f2b(v * g);
        } else {
          O0[row * 768 + cc] = v + Ef[row * 768 + cc];
        }
      }
    }
  }
}

// ---------------- depthwise causal conv(K=4) + SiLU -> flat + packed bf16 -------
__global__ __launch_bounds__(256)
void conv_silu(const float* __restrict__ xpu, const float* __restrict__ cw,
               u16* __restrict__ ub, u16* __restrict__ ubp) {
  const int c = blockIdx.x * 256 + threadIdx.x;
  const long m = blockIdx.y;
  const int t = (int)(m & (SEQ - 1));
  const float w0 = cw[c * 4 + 0], w1 = cw[c * 4 + 1], w2 = cw[c * 4 + 2], w3 = cw[c * 4 + 3];
  float acc = w3 * xpu[m * 1536 + c];
  if (t >= 1) acc += w2 * xpu[(m - 1) * 1536 + c];
  if (t >= 2) acc += w1 * xpu[(m - 2) * 1536 + c];
  if (t >= 3) acc += w0 * xpu[(m - 3) * 1536 + c];
  const float s = acc / (1.f + __expf(-acc));
  const u16 sb = f2b(s);
  ub[m * 1536 + c] = sb;
  ubp[pidx(m, c, 48)] = sb;
}

// ---------------- scan phase A: per-chunk (P, Q) from h=0, 4 states/thread ------
__global__ __launch_bounds__(256)
void scan_phaseA(const u16* __restrict__ dlt, const u16* __restrict__ ub,
                 const float* __restrict__ Bm, const float* __restrict__ A_log,
                 float* __restrict__ P, float* __restrict__ Q) {
  const int tid = threadIdx.x;
  const int cl = tid >> 2;
  const int sg = tid & 3;
  const int c = blockIdx.x * 64 + cl;
  const int b = blockIdx.y;
  const int ch = blockIdx.z;
  float a2[4];
#pragma unroll
  for (int j = 0; j < 4; ++j) a2[j] = -__expf(A_log[sg * 4 + j]) * LOG2E;
  float h[4] = {0.f, 0.f, 0.f, 0.f};
  float sumd = 0.f;
  const long base = (long)b * SEQ + (long)ch * CHUNK;
  for (int t = 0; t < CHUNK; ++t) {
    const long m = base + t;
    const float d = b2f(dlt[m * 1536 + c]);
    const float du = d * b2f(ub[m * 1536 + c]);
    sumd += d;
    const f32x4 Bv = *(const f32x4*)&Bm[m * 16 + sg * 4];
#pragma unroll
    for (int j = 0; j < 4; ++j) {
      const float e = exp2f(a2[j] * d);
      h[j] = e * h[j] + du * Bv[j];
    }
  }
  const long sb = (((long)b * NCHUNK + ch) * NST + sg * 4) * 1536 + c;
#pragma unroll
  for (int j = 0; j < 4; ++j) {
    Q[sb + (long)j * 1536] = h[j];
    P[sb + (long)j * 1536] = exp2f(a2[j] * sumd);
  }
}

// ---------------- scan phase B: serial combine over chunks (hs aliases P) -------
__global__ __launch_bounds__(256)
void scan_phaseB(float* __restrict__ P, const float* __restrict__ Q) {
  const long g = (long)blockIdx.x * 256 + threadIdx.x;   // BATCH*NST*INNER
  const int c = (int)(g % 1536);
  const int n = (int)((g / 1536) % NST);
  const int b = (int)(g / (1536 * NST));
  float h = 0.f;
  for (int ch = 0; ch < NCHUNK; ++ch) {
    const long idx = (((long)b * NCHUNK + ch) * NST + n) * 1536 + c;
    const float p = P[idx];
    const float q = Q[idx];
    P[idx] = h;              // hs written in place of P (read-before-write)
    h = p * h + q;
  }
}

// ---------------- scan phase C: replay with true h_start, emit ys packed --------
__global__ __launch_bounds__(256)
void scan_phaseC(const u16* __restrict__ dlt, const u16* __restrict__ ub,
                 const float* __restrict__ Bm, const float* __restrict__ Cm,
                 const float* __restrict__ A_log, const float* __restrict__ Dv,
                 const float* __restrict__ hs, u16* __restrict__ ysp) {
  const int tid = threadIdx.x;
  const int cl = tid >> 2;
  const int sg = tid & 3;
  const int c = blockIdx.x * 64 + cl;
  const int b = blockIdx.y;
  const int ch = blockIdx.z;
  float a2[4];
#pragma unroll
  for (int j = 0; j < 4; ++j) a2[j] = -__expf(A_log[sg * 4 + j]) * LOG2E;
  float h[4];
  const long sb = (((long)b * NCHUNK + ch) * NST + sg * 4) * 1536 + c;
#pragma unroll
  for (int j = 0; j < 4; ++j) h[j] = hs[sb + (long)j * 1536];
  const float Dc = Dv[c];
  const long base = (long)b * SEQ + (long)ch * CHUNK;
  for (int t = 0; t < CHUNK; ++t) {
    const long m = base + t;
    const float d = b2f(dlt[m * 1536 + c]);
    const float uu = b2f(ub[m * 1536 + c]);
    const float du = d * uu;
    const f32x4 Bv = *(const f32x4*)&Bm[m * 16 + sg * 4];
    const f32x4 Cv = *(const f32x4*)&Cm[m * 16 + sg * 4];
    float y = (sg == 0) ? Dc * uu : 0.f;
#pragma unroll
    for (int j = 0; j < 4; ++j) {
      const float e = exp2f(a2[j] * d);
      h[j] = e * h[j] + du * Bv[j];
      y += h[j] * Cv[j];
    }
    y += __shfl_xor(y, 1);
    y += __shfl_xor(y, 2);
    if (sg == 0) ysp[pidx(m, c, 48)] = f2b(y);
  }
}

extern "C" void kernel_launch(void* const* d_in, const int* in_sizes, int n_in,
                              void* d_out, int out_size, void* d_ws, size_t ws_size,
                              hipStream_t stream) {
  const float* x     = (const float*)d_in[0];
  const float* nw    = (const float*)d_in[1];
  const float* nb    = (const float*)d_in[2];
  const float* W_in  = (const float*)d_in[3];
  const float* cw    = (const float*)d_in[4];
  const float* W_xp  = (const float*)d_in[5];
  const float* A_log = (const float*)d_in[6];
  const float* Dv    = (const float*)d_in[7];
  const float* W_so  = (const float*)d_in[8];
  const float* W_out = (const float*)d_in[9];
  float* out = (float*)d_out;

  char* w = (char*)d_ws;
  auto alloc = [&](size_t bytes) {
    char* p = w;
    w += (bytes + 255) & ~(size_t)255;
    return p;
  };
  u16*   xnp   = (u16*)  alloc((size_t)MTOK * HID * 2);    // packed, KS=24
  u16*   WpIn  = (u16*)  alloc((size_t)3072 * 768 * 2);    // packed
  float* xpu   = (float*)alloc((size_t)MTOK * 1536 * 4);   // u half, fp32 flat
  u16*   sg    = (u16*)  alloc((size_t)MTOK * 1536 * 2);   // silu(gate), bf16 flat
  u16*   ub    = (u16*)  alloc((size_t)MTOK * 1536 * 2);   // silu(conv(u)), flat
  u16*   ubp   = (u16*)  alloc((size_t)MTOK * 1536 * 2);   // same, packed KS=48
  u16*   WpXp  = (u16*)  alloc((size_t)1664 * 1536 * 2);   // packed
  float* Bmv   = (float*)alloc((size_t)MTOK * 16 * 4);
  float* Cmv   = (float*)alloc((size_t)MTOK * 16 * 4);
  u16*   dlt   = (u16*)  alloc((size_t)MTOK * 1536 * 2);   // softplus(delta), flat
  float* P     = (float*)alloc((size_t)BATCH * NCHUNK * NST * 1536 * 4);  // becomes hs
  float* Q     = (float*)alloc((size_t)BATCH * NCHUNK * NST * 1536 * 4);
  u16*   ysp   = (u16*)  alloc((size_t)MTOK * 1536 * 2);   // packed KS=48
  u16*   WpSo  = (u16*)  alloc((size_t)1536 * 1536 * 2);   // packed
  u16*   zbp   = (u16*)  alloc((size_t)MTOK * 1536 * 2);   // packed KS=48
  u16*   WpOut = (u16*)  alloc((size_t)768 * 1536 * 2);    // packed

  ln_kernel<<<MTOK, 256, 0, stream>>>(x, nw, nb, xnp);
  pack_w<<<dim3(48, 24), 256, 0, stream>>>(W_in,  WpIn,  768,  3072);
  pack_w<<<dim3(26, 48), 256, 0, stream>>>(W_xp,  WpXp,  1536, 1568);
  pack_w<<<dim3(24, 48), 256, 0, stream>>>(W_so,  WpSo,  1536, 1536);
  pack_w<<<dim3(12, 48), 256, 0, stream>>>(W_out, WpOut, 1536, 768);

  // gemm0: 4096x3072, K=768.  FI=4 FJ=2: WM=64, NBLK=48 -> 1536 blocks
  gemm_pk<4, 2, 48, 0><<<1536, 256, 0, stream>>>(xnp, WpIn, xpu, nullptr, sg, nullptr, nullptr, 768, 3072);
  conv_silu<<<dim3(6, MTOK), 256, 0, stream>>>(xpu, cw, ub, ubp);
  // gemm1: 4096x1664, K=1536. FI=4 FJ=2: NBLK=26 -> 832 blocks
  gemm_pk<4, 2, 26, 1><<<832, 256, 0, stream>>>(ubp, WpXp, Bmv, Cmv, dlt, nullptr, nullptr, 1536, 1568);
  scan_phaseA<<<dim3(24, 2, NCHUNK), 256, 0, stream>>>(dlt, ub, Bmv, A_log, P, Q);
  scan_phaseB<<<192, 256, 0, stream>>>(P, Q);
  scan_phaseC<<<dim3(24, 2, NCHUNK), 256, 0, stream>>>(dlt, ub, Bmv, Cmv, A_log, Dv, P, ysp);
  // gemm2: 4096x1536, K=1536. FI=4 FJ=2: NBLK=24 -> 768 blocks
  gemm_pk<4, 2, 24, 2><<<768, 256, 0, stream>>>(ysp, WpSo, nullptr, nullptr, zbp, nullptr, sg, 1536, 1536);
  // gemm3: 4096x768,  K=1536. FI=2 FJ=2: WM=128, NBLK=12 -> 768 blocks
  gemm_pk<2, 2, 12, 3><<<768, 256, 0, stream>>>(zbp, WpOut, out, nullptr, nullptr, x, nullptr, 1536, 768);
}